// Round 5
// baseline (5414.050 us; speedup 1.0000x reference)
//
#include <hip/hip_runtime.h>
#include <hip/hip_fp16.h>
#include <hip/hip_cooperative_groups.h>

namespace cg = cooperative_groups;

#define BATCH 8
#define N 2048
#define NITERS 20
#define NBLK 1024
#define TPB 256
// rows total = 16384: 16 per block, 4 per wave; lane owns 32 cols (4 x Half8).

struct alignas(16) Half8 { __half h[8]; };

// ---------------------------------------------------------------------------
// Persistent cooperative kernel. Linear-domain Sinkhorn:
//   phase0: K = exp(z0) fp16, R = 1
//   iter:   invF_i = 1/sum_j K_ij R_j   (in-wave; also acc_j += K_ij*invF_i)
//           part[block] = block column partials  -> grid.sync
//           R_j = 1 / sum_chunks part            -> grid.sync
//   output: out_ij = K_ij * invF_i * R_j   (invF lives in registers)
// ---------------------------------------------------------------------------
__global__ __launch_bounds__(TPB, 4) void sinkhorn_coop(
    const float* __restrict__ z0, __half* __restrict__ K,
    float* __restrict__ part, float* __restrict__ R, float* __restrict__ out) {
  cg::grid_group grid = cg::this_grid();
  const int tid = threadIdx.x;
  const int lane = tid & 63;
  const int w = tid >> 6;
  const int bk = blockIdx.x;
  const int b = bk >> 7;                 // batch
  const int row0 = (bk & 127) * 16 + w * 4;  // first of my 4 rows (in batch)

  __shared__ float cls[4][N];  // 32 KB: per-wave column partials

  // ---- phase 0: K = exp(z0) fp16; R = 1 ----
  {
    const int gid = bk * TPB + tid;
    const float4* z4 = reinterpret_cast<const float4*>(z0);
    Half8* k8 = reinterpret_cast<Half8*>(K);
#pragma unroll 4
    for (int s = 0; s < 16; ++s) {
      const size_t i = (size_t)gid + (size_t)s * (NBLK * TPB);
      const float4 a = z4[2 * i];
      const float4 c = z4[2 * i + 1];
      Half8 hk;
      hk.h[0] = __float2half_rn(__expf(a.x));
      hk.h[1] = __float2half_rn(__expf(a.y));
      hk.h[2] = __float2half_rn(__expf(a.z));
      hk.h[3] = __float2half_rn(__expf(a.w));
      hk.h[4] = __float2half_rn(__expf(c.x));
      hk.h[5] = __float2half_rn(__expf(c.y));
      hk.h[6] = __float2half_rn(__expf(c.z));
      hk.h[7] = __float2half_rn(__expf(c.w));
      k8[i] = hk;
    }
    if (gid < BATCH * N) R[gid] = 1.0f;
  }
  grid.sync();

  float fi[4];  // invF for my 4 rows; persists into the output phase

  for (int it = 0; it < NITERS; ++it) {
    // R for my owned columns: cols c*512 + lane*8 .. +7
    float rv[4][8];
#pragma unroll
    for (int c = 0; c < 4; ++c) {
      const float4* rp = reinterpret_cast<const float4*>(
          R + (size_t)b * N + c * 512 + lane * 8);
      const float4 x = rp[0], y = rp[1];
      rv[c][0] = x.x; rv[c][1] = x.y; rv[c][2] = x.z; rv[c][3] = x.w;
      rv[c][4] = y.x; rv[c][5] = y.y; rv[c][6] = y.z; rv[c][7] = y.w;
    }
    float acc[4][8];
#pragma unroll
    for (int c = 0; c < 4; ++c)
#pragma unroll
      for (int k = 0; k < 8; ++k) acc[c][k] = 0.f;

    for (int pr = 0; pr < 2; ++pr) {  // 2 row-pairs
      const int r0 = row0 + pr * 2;
      const Half8* k0 =
          reinterpret_cast<const Half8*>(K + ((size_t)b * N + r0) * N);
      const Half8* k1 =
          reinterpret_cast<const Half8*>(K + ((size_t)b * N + r0 + 1) * N);
      Half8 kv0[4], kv1[4];
#pragma unroll
      for (int c = 0; c < 4; ++c) kv0[c] = k0[c * 64 + lane];
#pragma unroll
      for (int c = 0; c < 4; ++c) kv1[c] = k1[c * 64 + lane];
      float s0 = 0.f, s1 = 0.f;
#pragma unroll
      for (int c = 0; c < 4; ++c) {
        const __half2* h0 = reinterpret_cast<const __half2*>(&kv0[c]);
        const __half2* h1 = reinterpret_cast<const __half2*>(&kv1[c]);
#pragma unroll
        for (int q = 0; q < 4; ++q) {
          const float2 f0 = __half22float2(h0[q]);
          const float2 f1 = __half22float2(h1[q]);
          s0 += f0.x * rv[c][2 * q] + f0.y * rv[c][2 * q + 1];
          s1 += f1.x * rv[c][2 * q] + f1.y * rv[c][2 * q + 1];
        }
      }
#pragma unroll
      for (int o = 32; o > 0; o >>= 1) {
        s0 += __shfl_xor(s0, o, 64);
        s1 += __shfl_xor(s1, o, 64);
      }
      const float i0 = 1.0f / s0;
      const float i1 = 1.0f / s1;
      fi[pr * 2] = i0;
      fi[pr * 2 + 1] = i1;
#pragma unroll
      for (int c = 0; c < 4; ++c) {
        const __half2* h0 = reinterpret_cast<const __half2*>(&kv0[c]);
        const __half2* h1 = reinterpret_cast<const __half2*>(&kv1[c]);
#pragma unroll
        for (int q = 0; q < 4; ++q) {
          const float2 f0 = __half22float2(h0[q]);
          const float2 f1 = __half22float2(h1[q]);
          acc[c][2 * q] += f0.x * i0 + f1.x * i1;
          acc[c][2 * q + 1] += f0.y * i0 + f1.y * i1;
        }
      }
    }

    // wave partials -> LDS -> block partial (part[bk][0..N))
#pragma unroll
    for (int c = 0; c < 4; ++c) {
      float4* cp = reinterpret_cast<float4*>(&cls[w][c * 512 + lane * 8]);
      cp[0] = make_float4(acc[c][0], acc[c][1], acc[c][2], acc[c][3]);
      cp[1] = make_float4(acc[c][4], acc[c][5], acc[c][6], acc[c][7]);
    }
    __syncthreads();
    {
      float* pb = part + (size_t)bk * N;
#pragma unroll
      for (int s = 0; s < 8; ++s) {
        const int j = tid + s * 256;  // stride-256: conflict-free LDS reads
        pb[j] = cls[0][j] + cls[1][j] + cls[2][j] + cls[3][j];
      }
    }
    grid.sync();

    // combine: R[b][j] = 1 / sum_{c=0..127} part[b*128+c][j]; 4 lanes/output
    if (bk < 256) {
      const int gid = bk * TPB + tid;
      const int out_id = gid >> 2;  // b*N + j
      const int sub = gid & 3;
      const int bb = out_id >> 11;
      const int j = out_id & (N - 1);
      const float* p = part + ((size_t)(bb * 128 + sub * 32)) * N + j;
      float s = 0.f;
#pragma unroll
      for (int c = 0; c < 32; ++c) s += p[(size_t)c * N];
      s += __shfl_xor(s, 1, 64);
      s += __shfl_xor(s, 2, 64);
      if (sub == 0) R[out_id] = 1.0f / s;
    }
    grid.sync();
  }

  // ---- output: out = K * fi * R ----
  {
    float rv[4][8];
#pragma unroll
    for (int c = 0; c < 4; ++c) {
      const float4* rp = reinterpret_cast<const float4*>(
          R + (size_t)b * N + c * 512 + lane * 8);
      const float4 x = rp[0], y = rp[1];
      rv[c][0] = x.x; rv[c][1] = x.y; rv[c][2] = x.z; rv[c][3] = x.w;
      rv[c][4] = y.x; rv[c][5] = y.y; rv[c][6] = y.z; rv[c][7] = y.w;
    }
#pragma unroll
    for (int r = 0; r < 4; ++r) {
      const int row = row0 + r;
      const Half8* kr =
          reinterpret_cast<const Half8*>(K + ((size_t)b * N + row) * N);
      float* orow = out + ((size_t)b * N + row) * N;
      const float f = fi[r];
#pragma unroll
      for (int c = 0; c < 4; ++c) {
        const Half8 kv = kr[c * 64 + lane];
        const __half2* h = reinterpret_cast<const __half2*>(&kv);
        const float2 t0 = __half22float2(h[0]);
        const float2 t1 = __half22float2(h[1]);
        const float2 t2 = __half22float2(h[2]);
        const float2 t3 = __half22float2(h[3]);
        float4 o0, o1;
        o0.x = t0.x * f * rv[c][0]; o0.y = t0.y * f * rv[c][1];
        o0.z = t1.x * f * rv[c][2]; o0.w = t1.y * f * rv[c][3];
        o1.x = t2.x * f * rv[c][4]; o1.y = t2.y * f * rv[c][5];
        o1.z = t3.x * f * rv[c][6]; o1.w = t3.y * f * rv[c][7];
        float4* op = reinterpret_cast<float4*>(orow + c * 512 + lane * 8);
        op[0] = o0;
        op[1] = o1;
      }
    }
  }
}

// ======================= fallback path (R4, proven) ==========================
static __device__ __forceinline__ float wave_sum(float v) {
#pragma unroll
  for (int o = 32; o > 0; o >>= 1) v += __shfl_xor(v, o, 64);
  return v;
}

__global__ __launch_bounds__(256) void init_R_kernel(float* __restrict__ R) {
  const int i = blockIdx.x * 256 + threadIdx.x;
  if (i < (BATCH * N) / 4)
    reinterpret_cast<float4*>(R)[i] = make_float4(1.f, 1.f, 1.f, 1.f);
}

__global__ __launch_bounds__(256) void exp_transpose_kernel(
    const float* __restrict__ z0, __half* __restrict__ K,
    __half* __restrict__ KT, float* __restrict__ R) {
  __shared__ float t[64][65];
  const int b = blockIdx.z;
  const int R0 = blockIdx.y * 64, C0 = blockIdx.x * 64;
  const int q = threadIdx.x & 7;
  const int r = threadIdx.x >> 3;
  float4 za[2], zb[2];
#pragma unroll
  for (int p = 0; p < 2; ++p) {
    const float* src = z0 + ((size_t)b * N + R0 + r + 32 * p) * N + C0 + q * 8;
    za[p] = *reinterpret_cast<const float4*>(src);
    zb[p] = *reinterpret_cast<const float4*>(src + 4);
  }
#pragma unroll
  for (int p = 0; p < 2; ++p) {
    const int row = r + 32 * p;
    float e[8];
    e[0] = __expf(za[p].x); e[1] = __expf(za[p].y);
    e[2] = __expf(za[p].z); e[3] = __expf(za[p].w);
    e[4] = __expf(zb[p].x); e[5] = __expf(zb[p].y);
    e[6] = __expf(zb[p].z); e[7] = __expf(zb[p].w);
    Half8 hk;
#pragma unroll
    for (int c = 0; c < 8; ++c) hk.h[c] = __float2half_rn(e[c]);
    *reinterpret_cast<Half8*>(K + ((size_t)b * N + R0 + row) * N + C0 + q * 8) =
        hk;
#pragma unroll
    for (int c = 0; c < 8; ++c) t[row][q * 8 + c] = e[c];
  }
  __syncthreads();
#pragma unroll
  for (int p = 0; p < 2; ++p) {
    const int jr = r + 32 * p;
    Half8 hk;
#pragma unroll
    for (int c = 0; c < 8; ++c) hk.h[c] = __float2half_rn(t[q * 8 + c][jr]);
    *reinterpret_cast<Half8*>(KT + ((size_t)b * N + C0 + jr) * N + R0 + q * 8) =
        hk;
  }
  if (blockIdx.x == 0 && threadIdx.x < 16) {
    reinterpret_cast<float4*>(R + (size_t)b * N + R0)[threadIdx.x] =
        make_float4(1.f, 1.f, 1.f, 1.f);
  }
}

__global__ __launch_bounds__(256) void gemv_recip_kernel(
    const __half* __restrict__ M, const float* __restrict__ v,
    float* __restrict__ o) {
  const int lane = threadIdx.x & 63;
  const int w = threadIdx.x >> 6;
  const int b = blockIdx.y;
  const int row0 = (blockIdx.x * 4 + w) * 2;
  const float4* m0 =
      reinterpret_cast<const float4*>(M + ((size_t)b * N + row0) * N);
  const float4* m1 =
      reinterpret_cast<const float4*>(M + ((size_t)b * N + row0 + 1) * N);
  float4 ra[4], rb[4];
#pragma unroll
  for (int c = 0; c < 4; ++c) ra[c] = m0[c * 64 + lane];
#pragma unroll
  for (int c = 0; c < 4; ++c) rb[c] = m1[c * 64 + lane];
  const float4* v4 = reinterpret_cast<const float4*>(v + (size_t)b * N);
  float s0a = 0.f, s0b = 0.f, s1a = 0.f, s1b = 0.f;
#pragma unroll
  for (int c = 0; c < 4; ++c) {
    const float4 va = v4[c * 128 + lane * 2];
    const float4 vb = v4[c * 128 + lane * 2 + 1];
    const __half2* ha = reinterpret_cast<const __half2*>(&ra[c]);
    const __half2* hb = reinterpret_cast<const __half2*>(&rb[c]);
    float2 f;
    f = __half22float2(ha[0]); s0a += f.x * va.x; s0b += f.y * va.y;
    f = __half22float2(ha[1]); s0a += f.x * va.z; s0b += f.y * va.w;
    f = __half22float2(ha[2]); s0a += f.x * vb.x; s0b += f.y * vb.y;
    f = __half22float2(ha[3]); s0a += f.x * vb.z; s0b += f.y * vb.w;
    f = __half22float2(hb[0]); s1a += f.x * va.x; s1b += f.y * va.y;
    f = __half22float2(hb[1]); s1a += f.x * va.z; s1b += f.y * va.w;
    f = __half22float2(hb[2]); s1a += f.x * vb.x; s1b += f.y * vb.y;
    f = __half22float2(hb[3]); s1a += f.x * vb.z; s1b += f.y * vb.w;
  }
  float s0 = s0a + s0b, s1 = s1a + s1b;
#pragma unroll
  for (int off = 32; off > 0; off >>= 1) {
    s0 += __shfl_xor(s0, off, 64);
    s1 += __shfl_xor(s1, off, 64);
  }
  if (lane == 0) {
    *reinterpret_cast<float2*>(o + (size_t)b * N + row0) =
        make_float2(1.0f / s0, 1.0f / s1);
  }
}

__global__ __launch_bounds__(256) void final_fp16_kernel(
    const __half* __restrict__ K, const float* __restrict__ invF,
    const float* __restrict__ R, float* __restrict__ out) {
  const int lane = threadIdx.x & 63;
  const int w = threadIdx.x >> 6;
  const int b = blockIdx.y;
  const int row = blockIdx.x * 4 + w;
  const float fi = invF[(size_t)b * N + row];
  const float4* m4 =
      reinterpret_cast<const float4*>(K + ((size_t)b * N + row) * N);
  const float4* r4 = reinterpret_cast<const float4*>(R + (size_t)b * N);
  float4* o4 = reinterpret_cast<float4*>(out + ((size_t)b * N + row) * N);
#pragma unroll
  for (int c = 0; c < 4; ++c) {
    const float4 raw = m4[c * 64 + lane];
    const float4 va = r4[c * 128 + lane * 2];
    const float4 vb = r4[c * 128 + lane * 2 + 1];
    const __half2* h = reinterpret_cast<const __half2*>(&raw);
    float4 oa, ob;
    float2 f;
    f = __half22float2(h[0]); oa.x = f.x * fi * va.x; oa.y = f.y * fi * va.y;
    f = __half22float2(h[1]); oa.z = f.x * fi * va.z; oa.w = f.y * fi * va.w;
    f = __half22float2(h[2]); ob.x = f.x * fi * vb.x; ob.y = f.y * fi * vb.y;
    f = __half22float2(h[3]); ob.z = f.x * fi * vb.z; ob.w = f.y * fi * vb.w;
    o4[(c * 64 + lane) * 2 + 0] = oa;
    o4[(c * 64 + lane) * 2 + 1] = ob;
  }
}

template <int RPW>
__global__ __launch_bounds__(256) void row_fb_kernel(
    const float* __restrict__ z0, const float* __restrict__ R,
    float* __restrict__ invF, float* __restrict__ part) {
  constexpr int CH = N / RPW;
  const int lane = threadIdx.x & 63;
  const int w = threadIdx.x >> 6;
  const int b = blockIdx.y;
  const int chunk = blockIdx.x * 4 + w;
  const int row0 = chunk * RPW;
  const float4* r4 = reinterpret_cast<const float4*>(R + (size_t)b * N);
  float4 rv[8], acc[8];
#pragma unroll
  for (int k = 0; k < 8; ++k) {
    rv[k] = r4[lane + 64 * k];
    acc[k] = make_float4(0.f, 0.f, 0.f, 0.f);
  }
  for (int r = 0; r < RPW; ++r) {
    const int row = row0 + r;
    const float4* z4 =
        reinterpret_cast<const float4*>(z0 + ((size_t)b * N + row) * N);
    float4 zv[8];
#pragma unroll
    for (int k = 0; k < 8; ++k) {
      zv[k] = z4[lane + 64 * k];
      zv[k].x = __expf(zv[k].x); zv[k].y = __expf(zv[k].y);
      zv[k].z = __expf(zv[k].z); zv[k].w = __expf(zv[k].w);
    }
    float s0 = 0.f, s1 = 0.f;
#pragma unroll
    for (int k = 0; k < 8; ++k) {
      s0 += zv[k].x * rv[k].x; s1 += zv[k].y * rv[k].y;
      s0 += zv[k].z * rv[k].z; s1 += zv[k].w * rv[k].w;
    }
    const float inv = 1.0f / wave_sum(s0 + s1);
    if (lane == 0) invF[(size_t)b * N + row] = inv;
#pragma unroll
    for (int k = 0; k < 8; ++k) {
      acc[k].x += zv[k].x * inv; acc[k].y += zv[k].y * inv;
      acc[k].z += zv[k].z * inv; acc[k].w += zv[k].w * inv;
    }
  }
  float4* p4 = reinterpret_cast<float4*>(part + ((size_t)b * CH + chunk) * N);
#pragma unroll
  for (int k = 0; k < 8; ++k) p4[lane + 64 * k] = acc[k];
}

template <int CH>
__global__ __launch_bounds__(256) void combine_fb_kernel(
    const float* __restrict__ part, float* __restrict__ R) {
  const int gid = blockIdx.x * 256 + threadIdx.x;
  const int col_id = gid >> 2;
  const int sub = gid & 3;
  const int b = col_id >> 11;
  const int j = col_id & (N - 1);
  const float* p = part + (size_t)b * CH * N + j + (size_t)sub * N;
  float s = 0.f;
#pragma unroll
  for (int c = 0; c < CH / 4; ++c) s += p[(size_t)c * 4 * N];
  s += __shfl_xor(s, 1, 64);
  s += __shfl_xor(s, 2, 64);
  if (sub == 0) R[col_id] = 1.0f / s;
}

__global__ __launch_bounds__(256) void final_fb_kernel(
    const float* __restrict__ z0, const float* __restrict__ invF,
    const float* __restrict__ R, float* __restrict__ out) {
  const int b = blockIdx.y;
  const int row = blockIdx.x;
  const float fi = invF[(size_t)b * N + row];
  const float4* z4 =
      reinterpret_cast<const float4*>(z0 + ((size_t)b * N + row) * N);
  const float4* r4 = reinterpret_cast<const float4*>(R + (size_t)b * N);
  float4* o4 = reinterpret_cast<float4*>(out + ((size_t)b * N + row) * N);
#pragma unroll
  for (int k = 0; k < 2; ++k) {
    const int i = threadIdx.x + 256 * k;
    const float4 z = z4[i];
    const float4 r = r4[i];
    float4 o;
    o.x = __expf(z.x) * fi * r.x; o.y = __expf(z.y) * fi * r.y;
    o.z = __expf(z.z) * fi * r.z; o.w = __expf(z.w) * fi * r.w;
    o4[i] = o;
  }
}

extern "C" void kernel_launch(void* const* d_in, const int* in_sizes, int n_in,
                              void* d_out, int out_size, void* d_ws,
                              size_t ws_size, hipStream_t stream) {
  const float* z0 = (const float*)d_in[0];
  float* out = (float*)d_out;
  const size_t KE = (size_t)BATCH * N * N;

  // ---- primary: persistent cooperative kernel ----
  bool done = false;
  const size_t coop_need = KE * sizeof(__half) +
                           (size_t)NBLK * N * sizeof(float) +
                           (size_t)BATCH * N * sizeof(float);
  if (ws_size >= coop_need) {
    __half* K = (__half*)d_ws;
    float* part = (float*)((char*)d_ws + KE * sizeof(__half));
    float* R = part + (size_t)NBLK * N;
    void* args[5];
    args[0] = (void*)&z0;
    args[1] = (void*)&K;
    args[2] = (void*)&part;
    args[3] = (void*)&R;
    args[4] = (void*)&out;
    hipError_t err = hipLaunchCooperativeKernel(
        reinterpret_cast<const void*>(&sinkhorn_coop), dim3(NBLK), dim3(TPB),
        args, 0, stream);
    done = (err == hipSuccess);
  }
  if (done) return;

  // ---- fallback 1: R4 proven multi-dispatch fp16 GEMV path ----
  const size_t need_r4 =
      2 * KE * sizeof(__half) + 2 * (size_t)BATCH * N * sizeof(float);
  if (ws_size >= need_r4) {
    __half* K = (__half*)d_ws;
    __half* KT = K + KE;
    float* invF = (float*)(KT + KE);
    float* R = invF + (size_t)BATCH * N;
    exp_transpose_kernel<<<dim3(32, 32, 8), dim3(256), 0, stream>>>(z0, K, KT,
                                                                    R);
    for (int it = 0; it < NITERS; ++it) {
      gemv_recip_kernel<<<dim3(N / 8, BATCH), dim3(256), 0, stream>>>(K, R,
                                                                      invF);
      gemv_recip_kernel<<<dim3(N / 8, BATCH), dim3(256), 0, stream>>>(KT, invF,
                                                                      R);
    }
    final_fp16_kernel<<<dim3(N / 4, BATCH), dim3(256), 0, stream>>>(K, invF, R,
                                                                    out);
    return;
  }

  // ---- fallback 2: minimal-workspace path ----
  {
    float* invF = (float*)d_ws;
    float* R = invF + (size_t)BATCH * N;
    float* part = R + (size_t)BATCH * N;
    constexpr int RPW = 8;
    constexpr int CH = N / RPW;
    init_R_kernel<<<dim3(16), dim3(256), 0, stream>>>(R);
    for (int it = 0; it < NITERS; ++it) {
      row_fb_kernel<RPW>
          <<<dim3(N / (4 * RPW), BATCH), dim3(256), 0, stream>>>(z0, R, invF,
                                                                 part);
      combine_fb_kernel<CH>
          <<<dim3((BATCH * N * 4) / 256), dim3(256), 0, stream>>>(part, R);
    }
    final_fb_kernel<<<dim3(N, BATCH), dim3(256), 0, stream>>>(z0, invF, R,
                                                              out);
  }
}

// Round 6
// 396.190 us; speedup vs baseline: 13.6653x; 13.6653x over previous
//
#include <hip/hip_runtime.h>
#include <hip/hip_fp16.h>

#define BATCH 8
#define N 2048
#define NITERS 20

// ---------------------------------------------------------------------------
// Linear-domain Sinkhorn (matrix scaling), fp16 K, fused col-partials:
//   K = exp(z0) fp16                      [fused with iteration-1 row pass]
//   iter: invF_i = 1/sum_j K_ij R_j       (row GEMV, one K read)
//         part[blk][j] = sum_{i in blk} K_ij invF_i   (register+LDS partials)
//         R_j = 1 / sum_blk part[blk][j]  (tiny combine kernel)
//   out_ij = K_ij * invF_i * R_j
// Per-iter traffic: 67 MB K (L3-resident) + 16 MB partial round-trip,
// vs 134 MB for the K/KT two-GEMV scheme. KT and the transpose are gone.
// Inner-loop math identical to R5's verified coop body (absmax 1.2e-4).
// ---------------------------------------------------------------------------

struct alignas(16) Half8 { __half h[8]; };

// Blocks: (128, BATCH); 4 waves; wave owns 4 rows; lane owns 32 cols
// (4 groups of 8: cols c*512 + lane*8). Writes invF + per-block col partials.
__global__ __launch_bounds__(256) void row_part_kernel(
    const __half* __restrict__ K, const float* __restrict__ R,
    float* __restrict__ invF, float* __restrict__ part) {
  const int tid = threadIdx.x;
  const int lane = tid & 63;
  const int w = tid >> 6;
  const int blk = blockIdx.x;
  const int b = blockIdx.y;
  const int row0 = blk * 16 + w * 4;

  __shared__ float cls[4][N];

  float rv[4][8];
#pragma unroll
  for (int c = 0; c < 4; ++c) {
    const float4* rp = reinterpret_cast<const float4*>(
        R + (size_t)b * N + c * 512 + lane * 8);
    const float4 x = rp[0], y = rp[1];
    rv[c][0] = x.x; rv[c][1] = x.y; rv[c][2] = x.z; rv[c][3] = x.w;
    rv[c][4] = y.x; rv[c][5] = y.y; rv[c][6] = y.z; rv[c][7] = y.w;
  }
  float acc[4][8];
#pragma unroll
  for (int c = 0; c < 4; ++c)
#pragma unroll
    for (int k = 0; k < 8; ++k) acc[c][k] = 0.f;

#pragma unroll
  for (int pr = 0; pr < 2; ++pr) {
    const int r0 = row0 + pr * 2;
    const Half8* k0 =
        reinterpret_cast<const Half8*>(K + ((size_t)b * N + r0) * N);
    const Half8* k1 =
        reinterpret_cast<const Half8*>(K + ((size_t)b * N + r0 + 1) * N);
    Half8 kv0[4], kv1[4];
#pragma unroll
    for (int c = 0; c < 4; ++c) kv0[c] = k0[c * 64 + lane];
#pragma unroll
    for (int c = 0; c < 4; ++c) kv1[c] = k1[c * 64 + lane];
    float s0 = 0.f, s1 = 0.f;
#pragma unroll
    for (int c = 0; c < 4; ++c) {
      const __half2* h0 = reinterpret_cast<const __half2*>(&kv0[c]);
      const __half2* h1 = reinterpret_cast<const __half2*>(&kv1[c]);
#pragma unroll
      for (int q = 0; q < 4; ++q) {
        const float2 f0 = __half22float2(h0[q]);
        const float2 f1 = __half22float2(h1[q]);
        s0 += f0.x * rv[c][2 * q] + f0.y * rv[c][2 * q + 1];
        s1 += f1.x * rv[c][2 * q] + f1.y * rv[c][2 * q + 1];
      }
    }
#pragma unroll
    for (int o = 32; o > 0; o >>= 1) {
      s0 += __shfl_xor(s0, o, 64);
      s1 += __shfl_xor(s1, o, 64);
    }
    const float i0 = 1.0f / s0;
    const float i1 = 1.0f / s1;
    if (lane == 0) {
      *reinterpret_cast<float2*>(invF + (size_t)b * N + r0) =
          make_float2(i0, i1);
    }
#pragma unroll
    for (int c = 0; c < 4; ++c) {
      const __half2* h0 = reinterpret_cast<const __half2*>(&kv0[c]);
      const __half2* h1 = reinterpret_cast<const __half2*>(&kv1[c]);
#pragma unroll
      for (int q = 0; q < 4; ++q) {
        const float2 f0 = __half22float2(h0[q]);
        const float2 f1 = __half22float2(h1[q]);
        acc[c][2 * q] += f0.x * i0 + f1.x * i1;
        acc[c][2 * q + 1] += f0.y * i0 + f1.y * i1;
      }
    }
  }

#pragma unroll
  for (int c = 0; c < 4; ++c) {
    float4* cp = reinterpret_cast<float4*>(&cls[w][c * 512 + lane * 8]);
    cp[0] = make_float4(acc[c][0], acc[c][1], acc[c][2], acc[c][3]);
    cp[1] = make_float4(acc[c][4], acc[c][5], acc[c][6], acc[c][7]);
  }
  __syncthreads();
  {
    float* pb = part + ((size_t)b * 128 + blk) * N;
#pragma unroll
    for (int s = 0; s < 8; ++s) {
      const int j = tid + s * 256;  // stride-256: conflict-free LDS reads
      pb[j] = cls[0][j] + cls[1][j] + cls[2][j] + cls[3][j];
    }
  }
}

// Iteration 1 fused with precompute: K = exp(z0); R == 1 so the dot needs no
// R loads. Same block/row/col decomposition as row_part_kernel.
__global__ __launch_bounds__(256) void exp_row1_kernel(
    const float* __restrict__ z0, __half* __restrict__ K,
    float* __restrict__ invF, float* __restrict__ part) {
  const int tid = threadIdx.x;
  const int lane = tid & 63;
  const int w = tid >> 6;
  const int blk = blockIdx.x;
  const int b = blockIdx.y;
  const int row0 = blk * 16 + w * 4;

  __shared__ float cls[4][N];

  float acc[4][8];
#pragma unroll
  for (int c = 0; c < 4; ++c)
#pragma unroll
    for (int k = 0; k < 8; ++k) acc[c][k] = 0.f;

#pragma unroll
  for (int pr = 0; pr < 2; ++pr) {
    const int r0 = row0 + pr * 2;
    const float4* zr0 =
        reinterpret_cast<const float4*>(z0 + ((size_t)b * N + r0) * N);
    const float4* zr1 =
        reinterpret_cast<const float4*>(z0 + ((size_t)b * N + r0 + 1) * N);
    Half8* kw0 = reinterpret_cast<Half8*>(K + ((size_t)b * N + r0) * N);
    Half8* kw1 = reinterpret_cast<Half8*>(K + ((size_t)b * N + r0 + 1) * N);
    Half8 kv0[4], kv1[4];
#pragma unroll
    for (int c = 0; c < 4; ++c) {
      const float4 a0 = zr0[c * 128 + lane * 2];
      const float4 a1 = zr0[c * 128 + lane * 2 + 1];
      const float4 b0 = zr1[c * 128 + lane * 2];
      const float4 b1 = zr1[c * 128 + lane * 2 + 1];
      kv0[c].h[0] = __float2half_rn(__expf(a0.x));
      kv0[c].h[1] = __float2half_rn(__expf(a0.y));
      kv0[c].h[2] = __float2half_rn(__expf(a0.z));
      kv0[c].h[3] = __float2half_rn(__expf(a0.w));
      kv0[c].h[4] = __float2half_rn(__expf(a1.x));
      kv0[c].h[5] = __float2half_rn(__expf(a1.y));
      kv0[c].h[6] = __float2half_rn(__expf(a1.z));
      kv0[c].h[7] = __float2half_rn(__expf(a1.w));
      kv1[c].h[0] = __float2half_rn(__expf(b0.x));
      kv1[c].h[1] = __float2half_rn(__expf(b0.y));
      kv1[c].h[2] = __float2half_rn(__expf(b0.z));
      kv1[c].h[3] = __float2half_rn(__expf(b0.w));
      kv1[c].h[4] = __float2half_rn(__expf(b1.x));
      kv1[c].h[5] = __float2half_rn(__expf(b1.y));
      kv1[c].h[6] = __float2half_rn(__expf(b1.z));
      kv1[c].h[7] = __float2half_rn(__expf(b1.w));
      kw0[c * 64 + lane] = kv0[c];
      kw1[c * 64 + lane] = kv1[c];
    }
    // dot with R = 1 (use fp16-rounded values: consistent with later iters)
    float s0 = 0.f, s1 = 0.f;
#pragma unroll
    for (int c = 0; c < 4; ++c) {
      const __half2* h0 = reinterpret_cast<const __half2*>(&kv0[c]);
      const __half2* h1 = reinterpret_cast<const __half2*>(&kv1[c]);
#pragma unroll
      for (int q = 0; q < 4; ++q) {
        const float2 f0 = __half22float2(h0[q]);
        const float2 f1 = __half22float2(h1[q]);
        s0 += f0.x + f0.y;
        s1 += f1.x + f1.y;
      }
    }
#pragma unroll
    for (int o = 32; o > 0; o >>= 1) {
      s0 += __shfl_xor(s0, o, 64);
      s1 += __shfl_xor(s1, o, 64);
    }
    const float i0 = 1.0f / s0;
    const float i1 = 1.0f / s1;
    if (lane == 0) {
      *reinterpret_cast<float2*>(invF + (size_t)b * N + r0) =
          make_float2(i0, i1);
    }
#pragma unroll
    for (int c = 0; c < 4; ++c) {
      const __half2* h0 = reinterpret_cast<const __half2*>(&kv0[c]);
      const __half2* h1 = reinterpret_cast<const __half2*>(&kv1[c]);
#pragma unroll
      for (int q = 0; q < 4; ++q) {
        const float2 f0 = __half22float2(h0[q]);
        const float2 f1 = __half22float2(h1[q]);
        acc[c][2 * q] += f0.x * i0 + f1.x * i1;
        acc[c][2 * q + 1] += f0.y * i0 + f1.y * i1;
      }
    }
  }

#pragma unroll
  for (int c = 0; c < 4; ++c) {
    float4* cp = reinterpret_cast<float4*>(&cls[w][c * 512 + lane * 8]);
    cp[0] = make_float4(acc[c][0], acc[c][1], acc[c][2], acc[c][3]);
    cp[1] = make_float4(acc[c][4], acc[c][5], acc[c][6], acc[c][7]);
  }
  __syncthreads();
  {
    float* pb = part + ((size_t)b * 128 + blk) * N;
#pragma unroll
    for (int s = 0; s < 8; ++s) {
      const int j = tid + s * 256;
      pb[j] = cls[0][j] + cls[1][j] + cls[2][j] + cls[3][j];
    }
  }
}

// R[b][j] = 1 / sum_{c=0..127} part[b*128+c][j]; 4 lanes per output.
// (verified ordering from R5: chunk = sub*32 + c)
__global__ __launch_bounds__(256) void combine_kernel(
    const float* __restrict__ part, float* __restrict__ R) {
  const int gid = blockIdx.x * 256 + threadIdx.x;
  const int out_id = gid >> 2;  // b*N + j
  const int sub = gid & 3;
  const int b = out_id >> 11;
  const int j = out_id & (N - 1);
  const float* p = part + ((size_t)(b * 128 + sub * 32)) * N + j;
  float s = 0.f;
#pragma unroll
  for (int c = 0; c < 32; ++c) s += p[(size_t)c * N];
  s += __shfl_xor(s, 1, 64);
  s += __shfl_xor(s, 2, 64);
  if (sub == 0) R[out_id] = 1.0f / s;
}

// out[b][i][j] = K[b][i][j] * invF[b][i] * R[b][j]
__global__ __launch_bounds__(256) void final_fp16_kernel(
    const __half* __restrict__ K, const float* __restrict__ invF,
    const float* __restrict__ R, float* __restrict__ out) {
  const int lane = threadIdx.x & 63;
  const int w = threadIdx.x >> 6;
  const int b = blockIdx.y;
  const int row = blockIdx.x * 4 + w;
  const float fi = invF[(size_t)b * N + row];
  const float4* m4 =
      reinterpret_cast<const float4*>(K + ((size_t)b * N + row) * N);
  const float4* r4 = reinterpret_cast<const float4*>(R + (size_t)b * N);
  float4* o4 = reinterpret_cast<float4*>(out + ((size_t)b * N + row) * N);
#pragma unroll
  for (int c = 0; c < 4; ++c) {
    const float4 raw = m4[c * 64 + lane];
    const float4 va = r4[c * 128 + lane * 2];
    const float4 vb = r4[c * 128 + lane * 2 + 1];
    const __half2* h = reinterpret_cast<const __half2*>(&raw);
    float4 oa, ob;
    float2 f;
    f = __half22float2(h[0]); oa.x = f.x * fi * va.x; oa.y = f.y * fi * va.y;
    f = __half22float2(h[1]); oa.z = f.x * fi * va.z; oa.w = f.y * fi * va.w;
    f = __half22float2(h[2]); ob.x = f.x * fi * vb.x; ob.y = f.y * fi * vb.y;
    f = __half22float2(h[3]); ob.z = f.x * fi * vb.z; ob.w = f.y * fi * vb.w;
    o4[(c * 64 + lane) * 2 + 0] = oa;
    o4[(c * 64 + lane) * 2 + 1] = ob;
  }
}

// ------------------------- fallback (small ws) ------------------------------
static __device__ __forceinline__ float wave_sum(float v) {
#pragma unroll
  for (int o = 32; o > 0; o >>= 1) v += __shfl_xor(v, o, 64);
  return v;
}

__global__ __launch_bounds__(256) void init_R_kernel(float* __restrict__ R) {
  const int i = blockIdx.x * 256 + threadIdx.x;
  if (i < (BATCH * N) / 4)
    reinterpret_cast<float4*>(R)[i] = make_float4(1.f, 1.f, 1.f, 1.f);
}

template <int RPW>
__global__ __launch_bounds__(256) void row_fb_kernel(
    const float* __restrict__ z0, const float* __restrict__ R,
    float* __restrict__ invF, float* __restrict__ part) {
  constexpr int CH = N / RPW;
  const int lane = threadIdx.x & 63;
  const int w = threadIdx.x >> 6;
  const int b = blockIdx.y;
  const int chunk = blockIdx.x * 4 + w;
  const int row0 = chunk * RPW;
  const float4* r4 = reinterpret_cast<const float4*>(R + (size_t)b * N);
  float4 rv[8], acc[8];
#pragma unroll
  for (int k = 0; k < 8; ++k) {
    rv[k] = r4[lane + 64 * k];
    acc[k] = make_float4(0.f, 0.f, 0.f, 0.f);
  }
  for (int r = 0; r < RPW; ++r) {
    const int row = row0 + r;
    const float4* z4 =
        reinterpret_cast<const float4*>(z0 + ((size_t)b * N + row) * N);
    float4 zv[8];
#pragma unroll
    for (int k = 0; k < 8; ++k) {
      zv[k] = z4[lane + 64 * k];
      zv[k].x = __expf(zv[k].x); zv[k].y = __expf(zv[k].y);
      zv[k].z = __expf(zv[k].z); zv[k].w = __expf(zv[k].w);
    }
    float s0 = 0.f, s1 = 0.f;
#pragma unroll
    for (int k = 0; k < 8; ++k) {
      s0 += zv[k].x * rv[k].x; s1 += zv[k].y * rv[k].y;
      s0 += zv[k].z * rv[k].z; s1 += zv[k].w * rv[k].w;
    }
    const float inv = 1.0f / wave_sum(s0 + s1);
    if (lane == 0) invF[(size_t)b * N + row] = inv;
#pragma unroll
    for (int k = 0; k < 8; ++k) {
      acc[k].x += zv[k].x * inv; acc[k].y += zv[k].y * inv;
      acc[k].z += zv[k].z * inv; acc[k].w += zv[k].w * inv;
    }
  }
  float4* p4 = reinterpret_cast<float4*>(part + ((size_t)b * CH + chunk) * N);
#pragma unroll
  for (int k = 0; k < 8; ++k) p4[lane + 64 * k] = acc[k];
}

template <int CH>
__global__ __launch_bounds__(256) void combine_fb_kernel(
    const float* __restrict__ part, float* __restrict__ R) {
  const int gid = blockIdx.x * 256 + threadIdx.x;
  const int col_id = gid >> 2;
  const int sub = gid & 3;
  const int b = col_id >> 11;
  const int j = col_id & (N - 1);
  const float* p = part + (size_t)b * CH * N + j + (size_t)sub * N;
  float s = 0.f;
#pragma unroll
  for (int c = 0; c < CH / 4; ++c) s += p[(size_t)c * 4 * N];
  s += __shfl_xor(s, 1, 64);
  s += __shfl_xor(s, 2, 64);
  if (sub == 0) R[col_id] = 1.0f / s;
}

__global__ __launch_bounds__(256) void final_fb_kernel(
    const float* __restrict__ z0, const float* __restrict__ invF,
    const float* __restrict__ R, float* __restrict__ out) {
  const int b = blockIdx.y;
  const int row = blockIdx.x;
  const float fi = invF[(size_t)b * N + row];
  const float4* z4 =
      reinterpret_cast<const float4*>(z0 + ((size_t)b * N + row) * N);
  const float4* r4 = reinterpret_cast<const float4*>(R + (size_t)b * N);
  float4* o4 = reinterpret_cast<float4*>(out + ((size_t)b * N + row) * N);
#pragma unroll
  for (int k = 0; k < 2; ++k) {
    const int i = threadIdx.x + 256 * k;
    const float4 z = z4[i];
    const float4 r = r4[i];
    float4 o;
    o.x = __expf(z.x) * fi * r.x; o.y = __expf(z.y) * fi * r.y;
    o.z = __expf(z.z) * fi * r.z; o.w = __expf(z.w) * fi * r.w;
    o4[i] = o;
  }
}

extern "C" void kernel_launch(void* const* d_in, const int* in_sizes, int n_in,
                              void* d_out, int out_size, void* d_ws,
                              size_t ws_size, hipStream_t stream) {
  const float* z0 = (const float*)d_in[0];
  float* out = (float*)d_out;
  const size_t KE = (size_t)BATCH * N * N;

  const size_t need = KE * sizeof(__half) +            // K (67 MB)
                      (size_t)1024 * N * sizeof(float) +  // part (8 MB)
                      2 * (size_t)BATCH * N * sizeof(float);  // R + invF

  if (ws_size >= need) {
    __half* K = (__half*)d_ws;
    float* part = (float*)((char*)d_ws + KE * sizeof(__half));
    float* R = part + (size_t)1024 * N;
    float* invF = R + (size_t)BATCH * N;

    // iteration 1 fused with K precompute (R = 1)
    exp_row1_kernel<<<dim3(128, BATCH), dim3(256), 0, stream>>>(z0, K, invF,
                                                                part);
    combine_kernel<<<dim3(256), dim3(256), 0, stream>>>(part, R);
    for (int it = 1; it < NITERS; ++it) {
      row_part_kernel<<<dim3(128, BATCH), dim3(256), 0, stream>>>(K, R, invF,
                                                                  part);
      combine_kernel<<<dim3(256), dim3(256), 0, stream>>>(part, R);
    }
    final_fp16_kernel<<<dim3(N / 4, BATCH), dim3(256), 0, stream>>>(K, invF, R,
                                                                    out);
  } else {
    // minimal-workspace fallback (fp32, on-the-fly exp)
    float* invF = (float*)d_ws;
    float* R = invF + (size_t)BATCH * N;
    float* part = R + (size_t)BATCH * N;
    constexpr int RPW = 8;
    constexpr int CH = N / RPW;
    init_R_kernel<<<dim3(16), dim3(256), 0, stream>>>(R);
    for (int it = 0; it < NITERS; ++it) {
      row_fb_kernel<RPW>
          <<<dim3(N / (4 * RPW), BATCH), dim3(256), 0, stream>>>(z0, R, invF,
                                                                 part);
      combine_fb_kernel<CH>
          <<<dim3((BATCH * N * 4) / 256), dim3(256), 0, stream>>>(part, R);
    }
    final_fb_kernel<<<dim3(N, BATCH), dim3(256), 0, stream>>>(z0, invF, R,
                                                              out);
  }
}